// Round 10
// baseline (120.882 us; speedup 1.0000x reference)
//
#include <hip/hip_runtime.h>
#include <hip/hip_bf16.h>

#define MARGIN  0.2f
#define NEG_INF -1e30f
#define POS_INF 1e30f

#define B_SZ 8192
#define D_SZ 128
#define CS   16                      // col splits (512 cols each)
#define PCS  32                      // partial columns = CS * 2 (per wave col-tile)
#define BLK_COLS 512
#define PHASE_COLS 64
#define NPH (BLK_COLS / PHASE_COLS)  // 8
#define NBUF 3                       // LDS ring, prefetch distance 2

typedef __bf16 bf16x8 __attribute__((ext_vector_type(8)));
typedef float  f32x4  __attribute__((ext_vector_type(4)));
typedef float  f32x16 __attribute__((ext_vector_type(16)));

// ---------------- Kernel 1: fp32 -> bf16 convert (8 elems/thread) ----------------
__global__ __launch_bounds__(256) void k_convert(const float* __restrict__ in,
                                                 __bf16* __restrict__ out) {
    int i = (blockIdx.x * 256 + threadIdx.x) * 8;
    float4 v0 = *reinterpret_cast<const float4*>(in + i);
    float4 v1 = *reinterpret_cast<const float4*>(in + i + 4);
    bf16x8 o;
    o[0] = (__bf16)v0.x; o[1] = (__bf16)v0.y; o[2] = (__bf16)v0.z; o[3] = (__bf16)v0.w;
    o[4] = (__bf16)v1.x; o[5] = (__bf16)v1.y; o[6] = (__bf16)v1.z; o[7] = (__bf16)v1.w;
    *reinterpret_cast<bf16x8*>(out + i) = o;
}

// ---------------- Kernel 2: fused GEMM + hard mining ----------------
// 1024 blocks = 64 rb (128 rows) x 16 cs (512 cols), XCD swizzle. 4 waves:
// wave role = (rowhalf h = w>>1 -> 64 rows as 2 A-strips in regs; coltile
// c = w&1 -> ONE 32-col B tile per phase). Each ds_read_b128 feeds 2 MFMA.
// B staged to LDS ring (3 x 16KB) via global_load_lds, chunk(tile,kf)=1KB
// lane-linear both sides (conflict-free). Counted-vmcnt pipeline with CLEAN
// FIFO: the only in-loop VMEM is staging (cid via LDS, rid/A preloaded), so
// end-of-phase vmcnt(4) keeps stage(p+2)'s 4 loads in flight across the
// barrier; vmcnt(0) only in the last two phases.
__global__ __launch_bounds__(256, 2) void k_mine(const __bf16* __restrict__ imb,
                                                 const int* __restrict__ ids,
                                                 float* __restrict__ wsmax,
                                                 float* __restrict__ wsmin) {
    __shared__ __bf16 bpanel[NBUF][PHASE_COLS * D_SZ];   // 3 x 16KB
    __shared__ int    ids_s[BLK_COLS];                   // 2KB

    const int bid = blockIdx.x;
    const int wg  = (bid & 7) * 128 + (bid >> 3);   // bijective (1024%8==0)
    const int rb  = wg & 63;
    const int cs  = wg >> 6;

    const int tid  = threadIdx.x;
    const int w    = tid >> 6;
    const int lane = tid & 63;
    const int half = lane >> 5;      // 0/1 -> K sub-chunk of fragments
    const int l5   = lane & 31;      // row (A) / col (B)

    const int h = w >> 1;            // row half (64 rows)
    const int c = w & 1;             // col tile within phase (32 cols)

    const int rowbase = rb * 128 + h * 64;
    const int col0    = cs * BLK_COLS;

    // staging role: wave w stages chunks [w*4, w*4+4): tile = w>>1, kf0 = (w&1)*4
    const int s_tile = w >> 1;
    const int s_kf0  = (w & 1) * 4;

    // col ids -> LDS (512 ints)
    *reinterpret_cast<int2*>(&ids_s[tid * 2]) =
        *reinterpret_cast<const int2*>(ids + col0 + tid * 2);

    // A fragments: 2 strips x 8 kf (row = l5, k = kf*16 + half*8 + j)
    bf16x8 afrag[2][8];
    #pragma unroll
    for (int st = 0; st < 2; ++st) {
        const __bf16* p = imb + (size_t)(rowbase + st * 32 + l5) * D_SZ + half * 8;
        #pragma unroll
        for (int kf = 0; kf < 8; ++kf)
            afrag[st][kf] = *reinterpret_cast<const bf16x8*>(p + kf * 16);
    }
    // row ids for C layout: row = (r&3) + 8*(r>>2) + 4*half
    int rid[2][16];
    #pragma unroll
    for (int st = 0; st < 2; ++st)
        #pragma unroll
        for (int r = 0; r < 16; ++r)
            rid[st][r] = ids[rowbase + st * 32 + (r & 3) + 8 * (r >> 2) + 4 * half];

    // prologue: stage phases 0 and 1 (all reg loads issued above -> FIFO tail
    // is exactly the 8 stage loads)
    #pragma unroll
    for (int pp = 0; pp < 2; ++pp) {
        const __bf16* src = imb + (size_t)(col0 + pp * PHASE_COLS + s_tile * 32 + l5) * D_SZ
                            + s_kf0 * 16 + half * 8;
        #pragma unroll
        for (int j = 0; j < 4; ++j)
            __builtin_amdgcn_global_load_lds(
                (const __attribute__((address_space(1))) unsigned int*)(src + j * 16),
                (__attribute__((address_space(3))) unsigned int*)(&bpanel[pp][(s_tile * 8 + s_kf0 + j) * 512]),
                16, 0, 0);
    }
    asm volatile("s_waitcnt vmcnt(4) lgkmcnt(0)" ::: "memory");  // phase-0 + ids_s landed
    __builtin_amdgcn_s_barrier();

    float mxn[2][16], mnp[2][16];
    #pragma unroll
    for (int st = 0; st < 2; ++st)
        #pragma unroll
        for (int r = 0; r < 16; ++r) { mxn[st][r] = NEG_INF; mnp[st][r] = POS_INF; }

    #pragma unroll 1
    for (int p = 0; p < NPH; ++p) {
        if (p + 2 < NPH) {   // stage(p+2); stays in flight past the barrier
            const int bs = (p + 2) % NBUF;
            const __bf16* src = imb + (size_t)(col0 + (p + 2) * PHASE_COLS + s_tile * 32 + l5) * D_SZ
                                + s_kf0 * 16 + half * 8;
            #pragma unroll
            for (int j = 0; j < 4; ++j)
                __builtin_amdgcn_global_load_lds(
                    (const __attribute__((address_space(1))) unsigned int*)(src + j * 16),
                    (__attribute__((address_space(3))) unsigned int*)(&bpanel[bs][(s_tile * 8 + s_kf0 + j) * 512]),
                    16, 0, 0);
        }
        const int buf = p % NBUF;
        const int cid = ids_s[p * PHASE_COLS + c * 32 + l5];   // LDS -> lgkmcnt only

        const __bf16* bbase = &bpanel[buf][c * 8 * 512] + (size_t)lane * 8;
        f32x16 acc0 = {}, acc1 = {};
        #pragma unroll
        for (int kf = 0; kf < 8; ++kf) {
            bf16x8 bfr = *reinterpret_cast<const bf16x8*>(bbase + kf * 512);
            acc0 = __builtin_amdgcn_mfma_f32_32x32x16_bf16(afrag[0][kf], bfr, acc0, 0, 0, 0);
            acc1 = __builtin_amdgcn_mfma_f32_32x32x16_bf16(afrag[1][kf], bfr, acc1, 0, 0, 0);
        }
        // diag dropped: raw diag = ||v||^2 >= 0, absorbed by min(0,.) in k_final
        #pragma unroll
        for (int r = 0; r < 16; ++r) {
            float s0 = acc0[r], s1 = acc1[r];
            bool  m0 = (rid[0][r] == cid);
            bool  m1 = (rid[1][r] == cid);
            mxn[0][r] = fmaxf(mxn[0][r], m0 ? NEG_INF : s0);
            mnp[0][r] = fminf(mnp[0][r], m0 ? s0 : POS_INF);
            mxn[1][r] = fmaxf(mxn[1][r], m1 ? NEG_INF : s1);
            mnp[1][r] = fminf(mnp[1][r], m1 ? s1 : POS_INF);
        }
        if (p + 2 < NPH) {
            asm volatile("s_waitcnt vmcnt(4)" ::: "memory");  // p+1 landed; p+2 in flight
        } else {
            asm volatile("s_waitcnt vmcnt(0)" ::: "memory");  // tail drain
        }
        __builtin_amdgcn_s_barrier();
    }

    // epilogue: reduce over 32 cols (masks <32 stay within the half), then
    // write per-(row, cs*2+c) partials; writers at l5==0
    #pragma unroll
    for (int st = 0; st < 2; ++st)
        #pragma unroll
        for (int r = 0; r < 16; ++r) {
            float mx = mxn[st][r];
            float mn = mnp[st][r];
            #pragma unroll
            for (int m = 1; m < 32; m <<= 1) {
                mx = fmaxf(mx, __shfl_xor(mx, m, 64));
                mn = fminf(mn, __shfl_xor(mn, m, 64));
            }
            if (l5 == 0) {
                int row = rowbase + st * 32 + (r & 3) + 8 * (r >> 2) + 4 * half;
                wsmax[(size_t)row * PCS + cs * 2 + c] = mx;
                wsmin[(size_t)row * PCS + cs * 2 + c] = mn;
            }
        }
}

// ---------------- Kernel 3: final reduce ----------------
__global__ __launch_bounds__(256) void k_final(const float* __restrict__ wsmax,
                                               const float* __restrict__ wsmin,
                                               float* __restrict__ out) {
    int r = blockIdx.x * 256 + threadIdx.x;
    float mx = NEG_INF;
    float mn = 0.0f;   // zeroed diagonal is always a positive candidate
    #pragma unroll
    for (int cc = 0; cc < PCS; cc += 4) {
        f32x4 vx = *reinterpret_cast<const f32x4*>(wsmax + (size_t)r * PCS + cc);
        f32x4 vn = *reinterpret_cast<const f32x4*>(wsmin + (size_t)r * PCS + cc);
        mx = fmaxf(mx, fmaxf(fmaxf(vx[0], vx[1]), fmaxf(vx[2], vx[3])));
        mn = fminf(mn, fminf(fminf(vn[0], vn[1]), fminf(vn[2], vn[3])));
    }
    float cost = fmaxf(MARGIN + mx - mn, 0.0f);
    #pragma unroll
    for (int m = 1; m < 64; m <<= 1)
        cost += __shfl_xor(cost, m, 64);
    __shared__ float part[4];
    if ((threadIdx.x & 63) == 0) part[threadIdx.x >> 6] = cost;
    __syncthreads();
    if (threadIdx.x == 0)
        atomicAdd(out, part[0] + part[1] + part[2] + part[3]);
}

extern "C" void kernel_launch(void* const* d_in, const int* in_sizes, int n_in,
                              void* d_out, int out_size, void* d_ws, size_t ws_size,
                              hipStream_t stream) {
    const float* im  = (const float*)d_in[0];
    const int*   ids = (const int*)d_in[1];
    float*       out = (float*)d_out;

    __bf16* imb   = (__bf16*)d_ws;                                    // 2 MB
    float*  wsmax = (float*)((char*)d_ws + (size_t)B_SZ * D_SZ * 2);  // 1 MB
    float*  wsmin = wsmax + (size_t)B_SZ * PCS;                       // 1 MB

    hipMemsetAsync(d_out, 0, sizeof(float), stream);

    k_convert<<<(B_SZ * D_SZ) / (256 * 8), 256, 0, stream>>>(im, imb);
    k_mine<<<64 * CS, 256, 0, stream>>>(imb, ids, wsmax, wsmin);
    k_final<<<B_SZ / 256, 256, 0, stream>>>(wsmax, wsmin, out);
}